// Round 11
// baseline (9340.997 us; speedup 1.0000x reference)
//
#include <hip/hip_runtime.h>
#include <hip/hip_bf16.h>

// ModalityEnhancedLSTM: B=64, S=1024, D=256, H=256.
// out = [hidden_seq (64*1024*256) | h_t (64*256) | c_t (64*256)] f32.
//
//  Round-11 structure: 8 WGs = 4 groups(16 batch rows) x 2 colWGs(128 j-cols).
//  Per WG: 9 waves. w0-7 compute (U slice 128 VGPRs in regs; 4 slices of 16
//  gate-cols each; 32 MFMAs/step), w8 service (publish peer-half h, hidden_seq
//  f32 stores, xp global_load_lds ring, counted vmcnt).
//  Exchange per step: own half of h via LDS htmp (barrier-ordered, no global);
//  peer half via PROVEN sc0 sc1 L3 path: w8 stores 4KB A-frag-layout block,
//  peer compute waves poll it directly into MFMA registers (per-dword nonzero
//  data-is-the-flag; -h stored, U pre-negated so mfma(-h,-U)=hU; -0.0 guard
//  keeps every bf16 nonzero). ONE peer per reader (no max-of-8 skew term).
//  Compute waves issue NO global stores -> their poll vmcnt(0) is clean.

#define BSH 16777216u   // 64*1024*256
#define BH  16384u

typedef short short8 __attribute__((ext_vector_type(8)));
typedef float float4_ __attribute__((ext_vector_type(4)));
typedef unsigned int uint2_ __attribute__((ext_vector_type(2)));
typedef unsigned int uint4_ __attribute__((ext_vector_type(4)));

static __device__ __forceinline__ unsigned short f2bf(float f) {
    unsigned int u = __builtin_bit_cast(unsigned int, f);
    u += 0x7FFFu + ((u >> 16) & 1u);
    return (unsigned short)(u >> 16);
}
static __device__ __forceinline__ float bf2f(unsigned short h) {
    unsigned int u = ((unsigned int)h) << 16;
    return __builtin_bit_cast(float, u);
}
static __device__ __forceinline__ uint4_ pack8(const unsigned short* t) {
    uint4_ v;
    v.x = (unsigned int)t[0] | ((unsigned int)t[1] << 16);
    v.y = (unsigned int)t[2] | ((unsigned int)t[3] << 16);
    v.z = (unsigned int)t[4] | ((unsigned int)t[5] << 16);
    v.w = (unsigned int)t[6] | ((unsigned int)t[7] << 16);
    return v;
}
static __device__ __forceinline__ unsigned umin_(unsigned a, unsigned b) {
    return a < b ? a : b;
}
static __device__ __forceinline__ void gload_lds16(const void* g, void* l) {
    __builtin_amdgcn_global_load_lds(
        (const __attribute__((address_space(1))) unsigned int*)g,
        (__attribute__((address_space(3))) unsigned int*)l, 16, 0, 0);
}
static __device__ __forceinline__ void barrier_lgkm() {
    asm volatile("s_waitcnt lgkmcnt(0)" ::: "memory");
    __builtin_amdgcn_s_barrier();
    asm volatile("" ::: "memory");
}

// ---------------- prep: W,(-U) -> bf16 frag layout; bias -> per-slice -------
__global__ void prep_kernel(const float* __restrict__ W, const float* __restrict__ U,
                            const float* __restrict__ bias,
                            unsigned short* __restrict__ Wbf, unsigned short* __restrict__ Ubf,
                            float* __restrict__ biasf) {
    int tid = blockIdx.x * blockDim.x + threadIdx.x;
    if (tid < 65536) {
        int idx = tid & 32767;
        const bool isU = (tid >= 32768);
        const float* src = isU ? U : W;
        unsigned short* dst = isU ? Ubf : Wbf;
        int sl = idx >> 9, kt = (idx >> 6) & 7, lane = idx & 63;
        int c = lane & 15, kgrp = lane >> 4;
        int m = sl >> 3, wv = sl & 7;
        int gatec = c >> 2, jj = c & 3;
        int ncol = gatec * 256 + 32 * m + 4 * wv + jj;
        unsigned short t8[8];
#pragma unroll
        for (int e = 0; e < 8; e++) {
            int k = kt * 32 + kgrp * 8 + e;
            float v = src[k * 1024 + ncol];
            t8[e] = f2bf(isU ? -v : v);
        }
        *(uint4_*)(dst + (size_t)idx * 8) = pack8(t8);
    } else if (tid < 66560) {
        int idx2 = tid - 65536;            // [0,1024)
        int sl = idx2 >> 4, c = idx2 & 15;
        int m = sl >> 3, wv = sl & 7, gatec = c >> 2, jj = c & 3;
        int ncol = gatec * 256 + 32 * m + 4 * wv + jj;
        biasf[idx2] = bias[ncol];
    }
}

// ---------------- xproj: xp = x @ W + bias, bf16, per-oldWG layout ----------
__global__ __launch_bounds__(512, 2)
void xproj_kernel(const float* __restrict__ x, const unsigned short* __restrict__ Wbf,
                  const float* __restrict__ biasf, unsigned short* __restrict__ xp) {
    const int bx = blockIdx.x;             // [0,1024)
    const int g = bx & 3, tile = bx >> 2;  // 256 tiles of 4 s each
    const int s0 = tile * 4;
    const int tidx = threadIdx.x;
    const int w = tidx >> 6, lane = tidx & 63;

    __shared__ unsigned short Afrag[4][8][64][8];  // [si][kt][lane][e] 32KB

    {   // stage x (f32 -> bf16 A-frags)
        int row = tidx >> 3;               // 0..63 = si*16 + r
        int kt = tidx & 7;
        int si = row >> 4, r = row & 15;
        int b = g * 16 + r, s = s0 + si;
        const float* px = x + ((size_t)b * 1024 + s) * 256 + kt * 32;
#pragma unroll
        for (int kg = 0; kg < 4; kg++) {
            float4_ v0 = *(const float4_*)(px + kg * 8);
            float4_ v1 = *(const float4_*)(px + kg * 8 + 4);
            unsigned short t8[8] = { f2bf(v0.x), f2bf(v0.y), f2bf(v0.z), f2bf(v0.w),
                                     f2bf(v1.x), f2bf(v1.y), f2bf(v1.z), f2bf(v1.w) };
            *(uint4_*)&Afrag[si][kt][kg * 16 + r][0] = pack8(t8);
        }
    }
    __syncthreads();

    float4_ acc[8][4];
#pragma unroll
    for (int q = 0; q < 8; q++) {
        int sl = w * 8 + q;
        float bv = biasf[sl * 16 + (lane & 15)];
#pragma unroll
        for (int si = 0; si < 4; si++) acc[q][si] = (float4_){bv, bv, bv, bv};
    }
#pragma unroll
    for (int kt = 0; kt < 8; kt++) {
        short8 a[4];
#pragma unroll
        for (int si = 0; si < 4; si++)
            a[si] = *(const short8*)&Afrag[si][kt][lane][0];
#pragma unroll
        for (int q = 0; q < 8; q++) {
            short8 bfr = *(const short8*)(Wbf + (((size_t)(w * 8 + q) * 8 + kt) * 64 + lane) * 8);
#pragma unroll
            for (int si = 0; si < 4; si++)
                acc[q][si] = __builtin_amdgcn_mfma_f32_16x16x32_bf16(a[si], bfr, acc[q][si], 0, 0, 0);
        }
    }
#pragma unroll
    for (int q = 0; q < 8; q++) {
        int sl = w * 8 + q;
        int wgx = g * 8 + (sl >> 3);
#pragma unroll
        for (int si = 0; si < 4; si++) {
            int s = s0 + si;
            unsigned int lo = (unsigned int)f2bf(acc[q][si].x) | ((unsigned int)f2bf(acc[q][si].y) << 16);
            unsigned int hi = (unsigned int)f2bf(acc[q][si].z) | ((unsigned int)f2bf(acc[q][si].w) << 16);
            uint2_ v = {lo, hi};
            *(uint2_*)(xp + ((((size_t)wgx * 1024 + s) * 8 + (sl & 7)) * 64 + lane) * 4) = v;
        }
    }
}

// ---------------- recurrent scan -------------------------------------------
__global__ __launch_bounds__(576, 1)
void lstm_kernel(const unsigned short* __restrict__ Ubf,
                 const unsigned short* __restrict__ xp,
                 const float* __restrict__ lam,
                 unsigned short* __restrict__ hbuf,   // zero-initialized
                 float* __restrict__ out) {
    const int bx = blockIdx.x;             // grid 8
    const int g = bx >> 1;                 // batch group 0..3
    const int p = bx & 1;                  // column half 0..1 (j-cols 128p..)
    const int tid = threadIdx.x;
    const int w = tid >> 6, lane = tid & 63;

    __shared__ float lamLDS[1024];
    __shared__ alignas(16) unsigned short htmp[2][16][136];        // -h, this WG's 128 cols
    __shared__ alignas(16) unsigned short xpring[4][4][8][64][4];  // 64KB ring

    for (int i = tid; i < 1024; i += 576) lamLDS[i] = lam[i];

    const int col = lane & 15;
    const int gatec = col >> 2, jj = col & 3;
    const int rr0 = (lane >> 4) * 4;
    const bool active = (gatec == 0);

    // per-wave slice constants: slice s -> q4 = 4w+s; c_s = q4>>3; idx_s = q4&7
    int cS[4], idS[4], jloc[4];
    if (w < 8) {
#pragma unroll
        for (int s = 0; s < 4; s++) {
            int q4 = 4 * w + s;
            cS[s] = q4 >> 3; idS[s] = q4 & 7;
            jloc[s] = cS[s] * 32 + idS[s] * 4 + jj;
        }
    }

    short8 u[4][8];
    if (w < 8) {
#pragma unroll
        for (int s = 0; s < 4; s++) {
            int sl = p * 32 + 4 * w + s;
#pragma unroll
            for (int kt = 0; kt < 8; kt++)
                u[s][kt] = *(const short8*)(Ubf + (((size_t)sl * 8 + kt) * 64 + lane) * 8);
        }
    }

    if (w == 8) {   // prologue: prefetch xp slots 0..2
        for (int tt = 0; tt < 3; tt++)
            for (int c = 0; c < 4; c++) {
                const char* src = (const char*)xp
                    + (((size_t)(g * 8 + p * 4 + c) * 1024 + tt) << 12) + (size_t)lane * 16;
                char* dst = (char*)&xpring[tt][c][0][0][0];
#pragma unroll
                for (int k = 0; k < 4; k++)
                    gload_lds16(src + k * 1024, dst + k * 1024);
            }
        asm volatile("s_waitcnt vmcnt(32)" ::: "memory");   // slot 0 ready
    }

    float cst[4][4];
#pragma unroll
    for (int s = 0; s < 4; s++)
#pragma unroll
        for (int q = 0; q < 4; q++) cst[s][q] = 0.f;

    barrier_lgkm();

    // peer poll pointer (slot t-1): advance 8192B per step
    const char* pf = (const char*)hbuf
        + (((size_t)g * 2048) + (1 - p)) * 4096 + (size_t)lane * 16 - 8192;
    // w8 publish pointer (slot t-1)
    char* hp = (char*)hbuf + (((size_t)g * 2048) + p) * 4096 + (size_t)lane * 16 - 8192;

    for (int t = 0; t < 1024; t++) {
        if (w < 8) {
            // --- LDS reads first (lgkm domain; overlap with vmcnt poll) ---
            unsigned long long xpd[4];
#pragma unroll
            for (int s = 0; s < 4; s++)
                xpd[s] = *(const unsigned long long*)&xpring[t & 3][cS[s]][idS[s]][lane][0];
            short8 fro[4];
            if (t > 0) {
#pragma unroll
                for (int b = 0; b < 4; b++)
                    fro[b] = *(const short8*)&htmp[(t - 1) & 1][lane & 15]
                                              [b * 32 + (lane >> 4) * 8];
            }
            float4_ acc[4];
#pragma unroll
            for (int s = 0; s < 4; s++) {
                acc[s].x = bf2f((unsigned short)(xpd[s] & 0xffff));
                acc[s].y = bf2f((unsigned short)((xpd[s] >> 16) & 0xffff));
                acc[s].z = bf2f((unsigned short)((xpd[s] >> 32) & 0xffff));
                acc[s].w = bf2f((unsigned short)(xpd[s] >> 48));
            }
            if (t > 0) {
                // --- poll peer 4KB block (proven sc0 sc1 L3 path) ---
                uint4_ r0, r1, r2, r3;
                unsigned bail = 0;
                for (;;) {
                    asm volatile(
                        "global_load_dwordx4 %0, %4, off sc0 sc1\n\t"
                        "global_load_dwordx4 %1, %4, off offset:1024 sc0 sc1\n\t"
                        "global_load_dwordx4 %2, %4, off offset:2048 sc0 sc1\n\t"
                        "global_load_dwordx4 %3, %4, off offset:3072 sc0 sc1\n\t"
                        "s_waitcnt vmcnt(0)"
                        : "=v"(r0), "=v"(r1), "=v"(r2), "=v"(r3)
                        : "v"(pf) : "memory");
                    __builtin_amdgcn_sched_barrier(0);
                    unsigned mm = umin_(
                        umin_(umin_(umin_(r0.x, r0.y), umin_(r0.z, r0.w)),
                              umin_(umin_(r1.x, r1.y), umin_(r1.z, r1.w))),
                        umin_(umin_(umin_(r2.x, r2.y), umin_(r2.z, r2.w)),
                              umin_(umin_(r3.x, r3.y), umin_(r3.z, r3.w))));
                    if (__all(mm != 0u)) break;
                    if (++bail > (1u << 22)) break;   // fail fast, never hang
                }
                short8 rp[4] = { __builtin_bit_cast(short8, r0), __builtin_bit_cast(short8, r1),
                                 __builtin_bit_cast(short8, r2), __builtin_bit_cast(short8, r3) };
                if (p == 0) {   // own = kb 0..3, peer = kb 4..7
#pragma unroll
                    for (int b = 0; b < 4; b++)
#pragma unroll
                        for (int s = 0; s < 4; s++)
                            acc[s] = __builtin_amdgcn_mfma_f32_16x16x32_bf16(fro[b], u[s][b], acc[s], 0, 0, 0);
#pragma unroll
                    for (int b = 0; b < 4; b++)
#pragma unroll
                        for (int s = 0; s < 4; s++)
                            acc[s] = __builtin_amdgcn_mfma_f32_16x16x32_bf16(rp[b], u[s][4 + b], acc[s], 0, 0, 0);
                } else {        // peer = kb 0..3, own = kb 4..7
#pragma unroll
                    for (int b = 0; b < 4; b++)
#pragma unroll
                        for (int s = 0; s < 4; s++)
                            acc[s] = __builtin_amdgcn_mfma_f32_16x16x32_bf16(rp[b], u[s][b], acc[s], 0, 0, 0);
#pragma unroll
                    for (int b = 0; b < 4; b++)
#pragma unroll
                        for (int s = 0; s < 4; s++)
                            acc[s] = __builtin_amdgcn_mfma_f32_16x16x32_bf16(fro[b], u[s][4 + b], acc[s], 0, 0, 0);
                }
            }

            float lamt = lamLDS[t];
#pragma unroll
            for (int s = 0; s < 4; s++) {
                float gv[4], fv[4], ggv[4], ov[4];
#pragma unroll
                for (int q = 0; q < 4; q++) {
                    float xg = acc[s][q];
                    float y = (gatec == 2) ? 2.f * xg : xg;
                    float sgm = 1.f / (1.f + __expf(-y));
                    gv[q] = (gatec == 2) ? 2.f * sgm - 1.f : sgm;
                }
#pragma unroll
                for (int q = 0; q < 4; q++) {
                    fv[q]  = __shfl(gv[q], lane + 4, 64);
                    ggv[q] = __shfl(gv[q], lane + 8, 64);
                    ov[q]  = __shfl(gv[q], lane + 12, 64);
                }
                if (active) {
#pragma unroll
                    for (int q = 0; q < 4; q++) {
                        float c = fv[q] * cst[s][q] + gv[q] * ggv[q] * lamt;
                        cst[s][q] = c;
                        float th = 2.f / (1.f + __expf(-2.f * c)) - 1.f;
                        float hq = ov[q] * th;
                        unsigned short b = f2bf(-hq);
                        if (b == 0) b = 0x8000u;   // -0.0: value 0, bits != 0
                        htmp[t & 1][rr0 + q][jloc[s]] = b;
                        if (t == 1023) {
                            size_t br = (size_t)g * 16 + rr0 + q;
                            int j = p * 128 + jloc[s];
                            out[BSH + br * 256 + j] = hq;
                            out[BSH + BH + br * 256 + j] = cst[s][q];
                        }
                    }
                }
            }
        } else if (w == 8) {
            if (t > 0) {
                // 1) publish h(t-1) in A-frag layout (4KB, fire-and-forget)
#pragma unroll
                for (int b = 0; b < 4; b++) {
                    uint4_ blk = *(const uint4_*)&htmp[(t - 1) & 1][lane & 15]
                                                  [b * 32 + (lane >> 4) * 8];
                    const char* dstp = hp + b * 1024;
                    asm volatile("global_store_dwordx4 %0, %1, off sc0 sc1"
                                 :: "v"(dstp), "v"(blk) : "memory");
                }
                // 2) hidden_seq f32 for step t-1
                int row = lane & 15, cg = lane >> 4;
                float* pr = out + (((size_t)(g * 16 + row)) << 18)
                            + ((size_t)(t - 1) << 8) + p * 128 + cg * 32;
#pragma unroll
                for (int i = 0; i < 4; i++) {
                    uint4_ v = *(const uint4_*)&htmp[(t - 1) & 1][row][cg * 32 + i * 8];
                    v.x ^= 0x80008000u; v.y ^= 0x80008000u;
                    v.z ^= 0x80008000u; v.w ^= 0x80008000u;   // -(-h) = h
                    float4_ f0 = { bf2f((unsigned short)(v.x & 0xffff)), bf2f((unsigned short)(v.x >> 16)),
                                   bf2f((unsigned short)(v.y & 0xffff)), bf2f((unsigned short)(v.y >> 16)) };
                    float4_ f1 = { bf2f((unsigned short)(v.z & 0xffff)), bf2f((unsigned short)(v.z >> 16)),
                                   bf2f((unsigned short)(v.w & 0xffff)), bf2f((unsigned short)(v.w >> 16)) };
                    *(float4_*)(pr + i * 8) = f0;
                    *(float4_*)(pr + i * 8 + 4) = f1;
                }
            }
            // 3) xp prefetch slot (t+3)
            if (t + 3 < 1024) {
                int slot = (t + 3) & 3;
                for (int c = 0; c < 4; c++) {
                    const char* src = (const char*)xp
                        + (((size_t)(g * 8 + p * 4 + c) * 1024 + (size_t)(t + 3)) << 12)
                        + (size_t)lane * 16;
                    char* dst = (char*)&xpring[slot][c][0][0][0];
#pragma unroll
                    for (int k = 0; k < 4; k++)
                        gload_lds16(src + k * 1024, dst + k * 1024);
                }
                // 12 stores + 16 gloads this step outstanding; everything older
                // (incl. slot t+1's gloads) must retire:
                asm volatile("s_waitcnt vmcnt(28)" ::: "memory");
            } else {
                asm volatile("s_waitcnt vmcnt(12)" ::: "memory");
            }
        }
        barrier_lgkm();
        pf += 8192;
        hp += 8192;
    }
    // epilogue: hidden_seq for t=1023 (final barrier above orders htmp[1])
    if (w == 8) {
        int row = lane & 15, cg = lane >> 4;
        float* pr = out + (((size_t)(g * 16 + row)) << 18)
                    + ((size_t)1023 << 8) + p * 128 + cg * 32;
#pragma unroll
        for (int i = 0; i < 4; i++) {
            uint4_ v = *(const uint4_*)&htmp[1][row][cg * 32 + i * 8];
            v.x ^= 0x80008000u; v.y ^= 0x80008000u;
            v.z ^= 0x80008000u; v.w ^= 0x80008000u;
            float4_ f0 = { bf2f((unsigned short)(v.x & 0xffff)), bf2f((unsigned short)(v.x >> 16)),
                           bf2f((unsigned short)(v.y & 0xffff)), bf2f((unsigned short)(v.y >> 16)) };
            float4_ f1 = { bf2f((unsigned short)(v.z & 0xffff)), bf2f((unsigned short)(v.z >> 16)),
                           bf2f((unsigned short)(v.w & 0xffff)), bf2f((unsigned short)(v.w >> 16)) };
            *(float4_*)(pr + i * 8) = f0;
            *(float4_*)(pr + i * 8 + 4) = f1;
        }
    }
}

__global__ void ws_too_small_kernel(float* out) {
    if (threadIdx.x == 0 && blockIdx.x == 0) out[0] = -777777.0f;
}

extern "C" void kernel_launch(void* const* d_in, const int* in_sizes, int n_in,
                              void* d_out, int out_size, void* d_ws, size_t ws_size,
                              hipStream_t stream) {
    const float* x    = (const float*)d_in[0];
    const float* lam  = (const float*)d_in[1];
    const float* W    = (const float*)d_in[2];
    const float* U    = (const float*)d_in[3];
    const float* bias = (const float*)d_in[4];
    float* out = (float*)d_out;

    const size_t NEED = (size_t)162 << 20;   // 2MiB prep + 32MiB hbuf + 128MiB xp
    if (ws_size < NEED) {
        ws_too_small_kernel<<<1, 64, 0, stream>>>(out);
        return;
    }
    char* ws = (char*)d_ws;
    unsigned short* Ubf   = (unsigned short*)(ws + (256 << 10));       // 512KB
    unsigned short* Wbf   = (unsigned short*)(ws + (768 << 10));       // 512KB
    float*          biasf = (float*)(ws + (1280 << 10));               // 4KB
    unsigned short* hbuf  = (unsigned short*)(ws + ((size_t)2 << 20)); // 32MiB
    unsigned short* xp    = (unsigned short*)(ws + ((size_t)34 << 20));// 128MiB

    hipMemsetAsync(hbuf, 0, (size_t)32 << 20, stream);   // sentinel for data-poll
    prep_kernel<<<260, 256, 0, stream>>>(W, U, bias, Wbf, Ubf, biasf);
    xproj_kernel<<<1024, 512, 0, stream>>>(x, Wbf, biasf, xp);
    lstm_kernel<<<8, 576, 0, stream>>>(Ubf, xp, lam, hbuf, out);
}

// Round 12
// 5705.156 us; speedup vs baseline: 1.6373x; 1.6373x over previous
//
#include <hip/hip_runtime.h>
#include <hip/hip_bf16.h>

// ModalityEnhancedLSTM: B=64, S=1024, D=256, H=256.
// out = [hidden_seq (64*1024*256) | h_t (64*256) | c_t (64*256)] f32.
//
//  Round-12: 4-WAY GROUP INTERLEAVE to hide L3 exchange latency.
//  8 WGs (colWG m = 32 j-cols each), 9 waves: w0-7 compute, w8 publisher.
//  Each iteration = 4 phases; phase g advances batch-group g by one step.
//  Group g's h(t) published during phase g (w8: LDS data-flag detect ->
//  16B sc0 sc1 stores, A-frag layout); needed again only at phase g of the
//  NEXT iteration (~3 phases later) -> exchange latency fully hidden.
//  Readers prefetch h+xp as a 9-load register batch issued ~2 phases before
//  use: counted vmcnt(9) fast path; regs ZEROED at issue so un-landed data
//  reads as 0 -> per-dword flag fails -> bounded respin (loads+vmcnt(0) in
//  one asm). xp needs no flag: issued FIRST in batch, vmem retires in
//  order, so h-flag-pass implies xp landed. -h stored (U pre-negated),
//  -0.0 guard keeps every bf16 nonzero; 16B stores are atomic so per-dword
//  nonzero == published. One lgkm-only barrier per iteration.

#define BSH 16777216u   // 64*1024*256
#define BH  16384u
#define XPG ((size_t)32 << 20)   // xp group stride: 8 oldwg * 1024 t * 4096 B

typedef short short8 __attribute__((ext_vector_type(8)));
typedef float float4_ __attribute__((ext_vector_type(4)));
typedef unsigned int uint2_ __attribute__((ext_vector_type(2)));
typedef unsigned int uint4_ __attribute__((ext_vector_type(4)));

static __device__ __forceinline__ unsigned short f2bf(float f) {
    unsigned int u = __builtin_bit_cast(unsigned int, f);
    u += 0x7FFFu + ((u >> 16) & 1u);
    return (unsigned short)(u >> 16);
}
static __device__ __forceinline__ float bf2f(unsigned short h) {
    unsigned int u = ((unsigned int)h) << 16;
    return __builtin_bit_cast(float, u);
}
static __device__ __forceinline__ uint4_ pack8(const unsigned short* t) {
    uint4_ v;
    v.x = (unsigned int)t[0] | ((unsigned int)t[1] << 16);
    v.y = (unsigned int)t[2] | ((unsigned int)t[3] << 16);
    v.z = (unsigned int)t[4] | ((unsigned int)t[5] << 16);
    v.w = (unsigned int)t[6] | ((unsigned int)t[7] << 16);
    return v;
}
static __device__ __forceinline__ unsigned umin_(unsigned a, unsigned b) {
    return a < b ? a : b;
}
static __device__ __forceinline__ unsigned pkmin16(unsigned a, unsigned b) {
    unsigned d;
    asm("v_pk_min_u16 %0, %1, %2" : "=v"(d) : "v"(a), "v"(b));
    return d;
}
static __device__ __forceinline__ void barrier_lgkm() {
    asm volatile("s_waitcnt lgkmcnt(0)" ::: "memory");
    __builtin_amdgcn_s_barrier();
    asm volatile("" ::: "memory");
}

// ---------------- prep: W,(-U) -> bf16 frag layout; bias -> per-slice -------
__global__ void prep_kernel(const float* __restrict__ W, const float* __restrict__ U,
                            const float* __restrict__ bias,
                            unsigned short* __restrict__ Wbf, unsigned short* __restrict__ Ubf,
                            float* __restrict__ biasf) {
    int tid = blockIdx.x * blockDim.x + threadIdx.x;
    if (tid < 65536) {
        int idx = tid & 32767;
        const bool isU = (tid >= 32768);
        const float* src = isU ? U : W;
        unsigned short* dst = isU ? Ubf : Wbf;
        int sl = idx >> 9, kt = (idx >> 6) & 7, lane = idx & 63;
        int c = lane & 15, kgrp = lane >> 4;
        int m = sl >> 3, wv = sl & 7;
        int gatec = c >> 2, jj = c & 3;
        int ncol = gatec * 256 + 32 * m + 4 * wv + jj;
        unsigned short t8[8];
#pragma unroll
        for (int e = 0; e < 8; e++) {
            int k = kt * 32 + kgrp * 8 + e;
            float v = src[k * 1024 + ncol];
            t8[e] = f2bf(isU ? -v : v);
        }
        *(uint4_*)(dst + (size_t)idx * 8) = pack8(t8);
    } else if (tid < 66560) {
        int idx2 = tid - 65536;            // [0,1024)
        int sl = idx2 >> 4, c = idx2 & 15;
        int m = sl >> 3, wv = sl & 7, gatec = c >> 2, jj = c & 3;
        int ncol = gatec * 256 + 32 * m + 4 * wv + jj;
        biasf[idx2] = bias[ncol];
    }
}

// ---------------- xproj: xp = x @ W + bias, bf16, per-oldWG layout ----------
__global__ __launch_bounds__(512, 2)
void xproj_kernel(const float* __restrict__ x, const unsigned short* __restrict__ Wbf,
                  const float* __restrict__ biasf, unsigned short* __restrict__ xp) {
    const int bx = blockIdx.x;             // [0,1024)
    const int g = bx & 3, tile = bx >> 2;  // 256 tiles of 4 s each
    const int s0 = tile * 4;
    const int tidx = threadIdx.x;
    const int w = tidx >> 6, lane = tidx & 63;

    __shared__ unsigned short Afrag[4][8][64][8];  // [si][kt][lane][e] 32KB

    {   // stage x (f32 -> bf16 A-frags)
        int row = tidx >> 3;               // 0..63 = si*16 + r
        int kt = tidx & 7;
        int si = row >> 4, r = row & 15;
        int b = g * 16 + r, s = s0 + si;
        const float* px = x + ((size_t)b * 1024 + s) * 256 + kt * 32;
#pragma unroll
        for (int kg = 0; kg < 4; kg++) {
            float4_ v0 = *(const float4_*)(px + kg * 8);
            float4_ v1 = *(const float4_*)(px + kg * 8 + 4);
            unsigned short t8[8] = { f2bf(v0.x), f2bf(v0.y), f2bf(v0.z), f2bf(v0.w),
                                     f2bf(v1.x), f2bf(v1.y), f2bf(v1.z), f2bf(v1.w) };
            *(uint4_*)&Afrag[si][kt][kg * 16 + r][0] = pack8(t8);
        }
    }
    __syncthreads();

    float4_ acc[8][4];
#pragma unroll
    for (int q = 0; q < 8; q++) {
        int sl = w * 8 + q;
        float bv = biasf[sl * 16 + (lane & 15)];
#pragma unroll
        for (int si = 0; si < 4; si++) acc[q][si] = (float4_){bv, bv, bv, bv};
    }
#pragma unroll
    for (int kt = 0; kt < 8; kt++) {
        short8 a[4];
#pragma unroll
        for (int si = 0; si < 4; si++)
            a[si] = *(const short8*)&Afrag[si][kt][lane][0];
#pragma unroll
        for (int q = 0; q < 8; q++) {
            short8 bfr = *(const short8*)(Wbf + (((size_t)(w * 8 + q) * 8 + kt) * 64 + lane) * 8);
#pragma unroll
            for (int si = 0; si < 4; si++)
                acc[q][si] = __builtin_amdgcn_mfma_f32_16x16x32_bf16(a[si], bfr, acc[q][si], 0, 0, 0);
        }
    }
#pragma unroll
    for (int q = 0; q < 8; q++) {
        int sl = w * 8 + q;
        int wgx = g * 8 + (sl >> 3);
#pragma unroll
        for (int si = 0; si < 4; si++) {
            int s = s0 + si;
            unsigned int lo = (unsigned int)f2bf(acc[q][si].x) | ((unsigned int)f2bf(acc[q][si].y) << 16);
            unsigned int hi = (unsigned int)f2bf(acc[q][si].z) | ((unsigned int)f2bf(acc[q][si].w) << 16);
            uint2_ v = {lo, hi};
            *(uint2_*)(xp + ((((size_t)wgx * 1024 + s) * 8 + (sl & 7)) * 64 + lane) * 4) = v;
        }
    }
}

// ---------------- recurrent scan -------------------------------------------
#define UMIN4(v) umin_(umin_((v).x, (v).y), umin_((v).z, (v).w))
#define MINALL(a0,a1,a2,a3,a4,a5,a6,a7) \
    umin_(umin_(umin_(UMIN4(a0), UMIN4(a1)), umin_(UMIN4(a2), UMIN4(a3))), \
          umin_(umin_(UMIN4(a4), UMIN4(a5)), umin_(UMIN4(a6), UMIN4(a7))))

#define ISSUE9(a0,a1,a2,a3,a4,a5,a6,a7,xq,pb,pb4,xa) \
    asm volatile( \
        "global_load_dwordx2 %8, %11, off\n\t" \
        "global_load_dwordx4 %0, %9, off sc0 sc1\n\t" \
        "global_load_dwordx4 %1, %9, off offset:1024 sc0 sc1\n\t" \
        "global_load_dwordx4 %2, %9, off offset:2048 sc0 sc1\n\t" \
        "global_load_dwordx4 %3, %9, off offset:3072 sc0 sc1\n\t" \
        "global_load_dwordx4 %4, %10, off sc0 sc1\n\t" \
        "global_load_dwordx4 %5, %10, off offset:1024 sc0 sc1\n\t" \
        "global_load_dwordx4 %6, %10, off offset:2048 sc0 sc1\n\t" \
        "global_load_dwordx4 %7, %10, off offset:3072 sc0 sc1" \
        : "+v"(a0),"+v"(a1),"+v"(a2),"+v"(a3),"+v"(a4),"+v"(a5),"+v"(a6),"+v"(a7),"+v"(xq) \
        : "v"(pb), "v"(pb4), "v"(xa) : "memory")

#define RESPIN8(a0,a1,a2,a3,a4,a5,a6,a7,pb,pb4) \
    asm volatile( \
        "global_load_dwordx4 %0, %8, off sc0 sc1\n\t" \
        "global_load_dwordx4 %1, %8, off offset:1024 sc0 sc1\n\t" \
        "global_load_dwordx4 %2, %8, off offset:2048 sc0 sc1\n\t" \
        "global_load_dwordx4 %3, %8, off offset:3072 sc0 sc1\n\t" \
        "global_load_dwordx4 %4, %9, off sc0 sc1\n\t" \
        "global_load_dwordx4 %5, %9, off offset:1024 sc0 sc1\n\t" \
        "global_load_dwordx4 %6, %9, off offset:2048 sc0 sc1\n\t" \
        "global_load_dwordx4 %7, %9, off offset:3072 sc0 sc1\n\t" \
        "s_waitcnt vmcnt(0)" \
        : "+v"(a0),"+v"(a1),"+v"(a2),"+v"(a3),"+v"(a4),"+v"(a5),"+v"(a6),"+v"(a7) \
        : "v"(pb), "v"(pb4) : "memory")

#define PHASE(G, H0,H1,H2,H3,H4,H5,H6,H7, XQ) do {                               \
    asm volatile("s_waitcnt vmcnt(9)" ::: "memory");                             \
    __builtin_amdgcn_sched_barrier(0);                                           \
    if (t > 0) {                                                                 \
        if (!__all(MINALL(H0,H1,H2,H3,H4,H5,H6,H7) != 0u)) {                     \
            const char* pb_ = hbase + (G) * 8192;                                \
            unsigned bail_ = 0;                                                  \
            do {                                                                 \
                RESPIN8(H0,H1,H2,H3,H4,H5,H6,H7, pb_, pb_ + 4096);               \
                __builtin_amdgcn_sched_barrier(0);                               \
                if (++bail_ > (1u << 22)) break;                                 \
            } while (!__all(MINALL(H0,H1,H2,H3,H4,H5,H6,H7) != 0u));             \
        }                                                                        \
    }                                                                            \
    unsigned long long xpd_ = XQ;                                                \
    float4_ acc0, acc1 = (float4_){0.f, 0.f, 0.f, 0.f};                          \
    acc0.x = bf2f((unsigned short)(xpd_ & 0xffff));                              \
    acc0.y = bf2f((unsigned short)((xpd_ >> 16) & 0xffff));                      \
    acc0.z = bf2f((unsigned short)((xpd_ >> 32) & 0xffff));                      \
    acc0.w = bf2f((unsigned short)(xpd_ >> 48));                                 \
    if (t > 0) {                                                                 \
        acc0 = __builtin_amdgcn_mfma_f32_16x16x32_bf16(__builtin_bit_cast(short8, H0), u[0], acc0, 0, 0, 0); \
        acc1 = __builtin_amdgcn_mfma_f32_16x16x32_bf16(__builtin_bit_cast(short8, H1), u[1], acc1, 0, 0, 0); \
        acc0 = __builtin_amdgcn_mfma_f32_16x16x32_bf16(__builtin_bit_cast(short8, H2), u[2], acc0, 0, 0, 0); \
        acc1 = __builtin_amdgcn_mfma_f32_16x16x32_bf16(__builtin_bit_cast(short8, H3), u[3], acc1, 0, 0, 0); \
        acc0 = __builtin_amdgcn_mfma_f32_16x16x32_bf16(__builtin_bit_cast(short8, H4), u[4], acc0, 0, 0, 0); \
        acc1 = __builtin_amdgcn_mfma_f32_16x16x32_bf16(__builtin_bit_cast(short8, H5), u[5], acc1, 0, 0, 0); \
        acc0 = __builtin_amdgcn_mfma_f32_16x16x32_bf16(__builtin_bit_cast(short8, H6), u[6], acc0, 0, 0, 0); \
        acc1 = __builtin_amdgcn_mfma_f32_16x16x32_bf16(__builtin_bit_cast(short8, H7), u[7], acc1, 0, 0, 0); \
    }                                                                            \
    {   /* zero set, reissue for group (G+2)&3 */                                \
        const int IG_ = ((G) + 2) & 3;                                           \
        const bool nxt_ = ((G) >= 2);                                            \
        const char* pb_ = (t == 0 && !nxt_) ? hb0                                \
                          : (hbase + (nxt_ ? 32768 : 0) + IG_ * 8192);           \
        const char* xa_ = (t == 1023 && nxt_) ? hb0                              \
                          : (xcur + (nxt_ ? 4096 : 0) + (size_t)IG_ * XPG);      \
        uint4_ z_ = {0u, 0u, 0u, 0u};                                            \
        H0 = z_; H1 = z_; H2 = z_; H3 = z_;                                      \
        H4 = z_; H5 = z_; H6 = z_; H7 = z_;                                      \
        XQ = 0ull;                                                               \
        ISSUE9(H0,H1,H2,H3,H4,H5,H6,H7, XQ, pb_, pb_ + 4096, xa_);               \
    }                                                                            \
    {   /* gates */                                                              \
        float lamt = lamLDS[t];                                                  \
        float gv[4], fv[4], ggv[4], ov[4];                                       \
        _Pragma("unroll")                                                        \
        for (int q = 0; q < 4; q++) {                                            \
            float xg = acc0[q] + acc1[q];                                        \
            float y = (gatec == 2) ? 2.f * xg : xg;                              \
            float sgm = 1.f / (1.f + __expf(-y));                                \
            gv[q] = (gatec == 2) ? 2.f * sgm - 1.f : sgm;                        \
        }                                                                        \
        _Pragma("unroll")                                                        \
        for (int q = 0; q < 4; q++) {                                            \
            fv[q]  = __shfl(gv[q], lane + 4, 64);                                \
            ggv[q] = __shfl(gv[q], lane + 8, 64);                                \
            ov[q]  = __shfl(gv[q], lane + 12, 64);                               \
        }                                                                        \
        if (active) {                                                            \
            _Pragma("unroll")                                                    \
            for (int q = 0; q < 4; q++) {                                        \
                float c_ = fv[q] * cst[G][q] + gv[q] * ggv[q] * lamt;            \
                cst[G][q] = c_;                                                  \
                float th = 2.f / (1.f + __expf(-2.f * c_)) - 1.f;                \
                float hq = ov[q] * th;                                           \
                unsigned short b_ = f2bf(-hq);                                   \
                if (b_ == 0) b_ = 0x8000u;                                       \
                htmp[G][t & 1][rr0 + q][4 * w + jj] = b_;                        \
                if (t == 1023) {                                                 \
                    size_t br = (size_t)(G) * 16 + rr0 + q;                      \
                    int j = m * 32 + 4 * w + jj;                                 \
                    out[BSH + br * 256 + j] = hq;                                \
                    out[BSH + BH + br * 256 + j] = cst[G][q];                    \
                }                                                                \
            }                                                                    \
        }                                                                        \
    }                                                                            \
} while (0)

__global__ __launch_bounds__(576, 1)
void lstm_kernel(const unsigned short* __restrict__ Ubf,
                 const unsigned short* __restrict__ xp,
                 const float* __restrict__ lam,
                 unsigned short* __restrict__ hbuf,   // zero-initialized
                 float* __restrict__ out) {
    const int m = blockIdx.x;              // colWG 0..7 (grid 8)
    const int tid = threadIdx.x;
    const int w = tid >> 6, lane = tid & 63;

    __shared__ float lamLDS[1024];
    __shared__ alignas(16) unsigned short htmp[4][2][16][40];  // -h bf16, zeroed

    for (int i = tid; i < 1024; i += 576) lamLDS[i] = lam[i];
    {
        unsigned int* hz = (unsigned int*)htmp;   // 2560 dwords
        for (int i = tid; i < 2560; i += 576) hz[i] = 0u;
    }

    const int col = lane & 15;
    const int gatec = col >> 2, jj = col & 3;
    const int rr0 = (lane >> 4) * 4;
    const bool active = (gatec == 0);

    short8 u[8];
    if (w < 8) {
        int sl = m * 8 + w;
#pragma unroll
        for (int kt = 0; kt < 8; kt++)
            u[kt] = *(const short8*)(Ubf + (((size_t)sl * 8 + kt) * 64 + lane) * 8);
    }

    float cst[4][4];
#pragma unroll
    for (int gg = 0; gg < 4; gg++)
#pragma unroll
        for (int q = 0; q < 4; q++) cst[gg][q] = 0.f;

    // rolling pointers
    const char* hb0 = (const char*)hbuf + (size_t)lane * 16;   // dummy target
    const char* hbase = (const char*)hbuf + (size_t)lane * 16 - 32768;  // slot t-1, group 0
    const char* xcur = (const char*)xp + ((size_t)m * 1024) * 4096
                     + (size_t)(w < 8 ? w : 0) * 512 + (size_t)lane * 8;  // (group0, t)

    barrier_lgkm();   // LDS init visible to all waves

    if (w < 8) {
        uint4_ hA0,hA1,hA2,hA3,hA4,hA5,hA6,hA7; unsigned long long xqA;
        uint4_ hB0,hB1,hB2,hB3,hB4,hB5,hB6,hB7; unsigned long long xqB;
        {   // prologue: set A <- (group0,t=0): dummy-h + xp_0(0); set B <- (group1,t=0)
            uint4_ z = {0u,0u,0u,0u};
            hA0=z;hA1=z;hA2=z;hA3=z;hA4=z;hA5=z;hA6=z;hA7=z; xqA=0ull;
            hB0=z;hB1=z;hB2=z;hB3=z;hB4=z;hB5=z;hB6=z;hB7=z; xqB=0ull;
            const char* xa0 = xcur;
            const char* xa1 = xcur + XPG;
            ISSUE9(hA0,hA1,hA2,hA3,hA4,hA5,hA6,hA7, xqA, hb0, hb0 + 4096, xa0);
            ISSUE9(hB0,hB1,hB2,hB3,hB4,hB5,hB6,hB7, xqB, hb0, hb0 + 4096, xa1);
        }
        for (int t = 0; t < 1024; t++) {
            PHASE(0, hA0,hA1,hA2,hA3,hA4,hA5,hA6,hA7, xqA);
            PHASE(1, hB0,hB1,hB2,hB3,hB4,hB5,hB6,hB7, xqB);
            PHASE(2, hA0,hA1,hA2,hA3,hA4,hA5,hA6,hA7, xqA);
            PHASE(3, hB0,hB1,hB2,hB3,hB4,hB5,hB6,hB7, xqB);
            barrier_lgkm();
            hbase += 32768;
            xcur += 4096;
        }
    } else if (w == 8) {
        // publisher + hidden_seq wave
        const int row = lane & 15, kg = lane >> 4;
        for (int t = 0; t < 1024; t++) {
#pragma unroll
            for (int G = 0; G < 4; G++) {
                volatile unsigned int* hp =
                    (volatile unsigned int*)&htmp[G][t & 1][row][kg * 8];
                bool done = false;
                unsigned bail = 0;
                while (!__all(done)) {
                    if (!done) {
                        unsigned a0 = hp[0], a1 = hp[1], a2 = hp[2], a3 = hp[3];
                        unsigned mm = pkmin16(pkmin16(a0, a1), pkmin16(a2, a3));
                        if (((mm & 0xffffu) != 0u) && ((mm >> 16) != 0u)) {
                            uint4_ blk = {a0, a1, a2, a3};
                            char* hd = (char*)hbuf + (((size_t)t * 4 + G) << 13)
                                     + (size_t)m * 1024 + (size_t)lane * 16;
                            asm volatile("global_store_dwordx4 %0, %1, off sc0 sc1"
                                         :: "v"(hd), "v"(blk) : "memory");
                            unsigned x0 = a0 ^ 0x80008000u, x1 = a1 ^ 0x80008000u;
                            unsigned x2 = a2 ^ 0x80008000u, x3 = a3 ^ 0x80008000u;
                            float4_ f0 = { bf2f((unsigned short)(x0 & 0xffff)), bf2f((unsigned short)(x0 >> 16)),
                                           bf2f((unsigned short)(x1 & 0xffff)), bf2f((unsigned short)(x1 >> 16)) };
                            float4_ f1 = { bf2f((unsigned short)(x2 & 0xffff)), bf2f((unsigned short)(x2 >> 16)),
                                           bf2f((unsigned short)(x3 & 0xffff)), bf2f((unsigned short)(x3 >> 16)) };
                            float* pr = out + (((size_t)(G * 16 + row)) << 18)
                                      + ((size_t)t << 8) + m * 32 + kg * 8;
                            *(float4_*)pr = f0;
                            *(float4_*)(pr + 4) = f1;
                            uint4_ z = {0u, 0u, 0u, 0u};
                            *(uint4_*)&htmp[G][t & 1][row][kg * 8] = z;  // reuse @ t+2
                            done = true;
                        }
                    }
                    if (++bail > (1u << 24)) break;
                }
            }
            barrier_lgkm();
        }
    } else {
        for (int t = 0; t < 1024; t++) barrier_lgkm();
    }
}

__global__ void ws_too_small_kernel(float* out) {
    if (threadIdx.x == 0 && blockIdx.x == 0) out[0] = -777777.0f;
}

extern "C" void kernel_launch(void* const* d_in, const int* in_sizes, int n_in,
                              void* d_out, int out_size, void* d_ws, size_t ws_size,
                              hipStream_t stream) {
    const float* x    = (const float*)d_in[0];
    const float* lam  = (const float*)d_in[1];
    const float* W    = (const float*)d_in[2];
    const float* U    = (const float*)d_in[3];
    const float* bias = (const float*)d_in[4];
    float* out = (float*)d_out;

    const size_t NEED = (size_t)162 << 20;   // 2MiB prep + 32MiB hbuf + 128MiB xp
    if (ws_size < NEED) {
        ws_too_small_kernel<<<1, 64, 0, stream>>>(out);
        return;
    }
    char* ws = (char*)d_ws;
    unsigned short* Ubf   = (unsigned short*)(ws + (256 << 10));       // 512KB
    unsigned short* Wbf   = (unsigned short*)(ws + (768 << 10));       // 512KB
    float*          biasf = (float*)(ws + (1280 << 10));               // 4KB
    unsigned short* hbuf  = (unsigned short*)(ws + ((size_t)2 << 20)); // 32MiB
    unsigned short* xp    = (unsigned short*)(ws + ((size_t)34 << 20));// 128MiB

    hipMemsetAsync(hbuf, 0, (size_t)32 << 20, stream);   // sentinel for data-poll
    prep_kernel<<<260, 256, 0, stream>>>(W, U, bias, Wbf, Ubf, biasf);
    xproj_kernel<<<1024, 512, 0, stream>>>(x, Wbf, biasf, xp);
    lstm_kernel<<<8, 576, 0, stream>>>(Ubf, xp, lam, hbuf, out);
}